// Round 20
// baseline (213.237 us; speedup 1.0000x reference)
//
#include <hip/hip_runtime.h>
#include <hip/hip_bf16.h>
#include <cstdint>
#include <cstddef>

// BitNet b1.58 attention block: B=2 S=2048 D=2048 H=16 HD=128.
// Projections via int8 MFMA (exact: int8 x ternary, |acc| <= 2048*127 < 2^24);
// attention via bf16 MFMA, parity-split-KV with a fused combine+quant pass.

#define BB 2
#define SS 2048
#define DD 2048
#define HH 16
#define HDD 128
#define MM (BB*SS)   // 4096 token rows

typedef __attribute__((ext_vector_type(8))) short bf16x8;
typedef __attribute__((ext_vector_type(4))) float f32x4;
typedef __attribute__((ext_vector_type(16))) float f32x16;
typedef __attribute__((ext_vector_type(4))) int   i32x4;
typedef unsigned short u16;
typedef unsigned int   u32;
typedef unsigned char  u8;
typedef signed char    s8;

#define MFMA(a,b,c)   __builtin_amdgcn_mfma_f32_16x16x32_bf16(a,b,c,0,0,0)
#define MFMA32(a,b,c) __builtin_amdgcn_mfma_f32_32x32x16_bf16(a,b,c,0,0,0)
#define MFMAI8(a,b,c) __builtin_amdgcn_mfma_i32_16x16x64_i8(a,b,c,0,0,0)

static __device__ __forceinline__ u16 f2bf(float f) {
  // round-to-nearest-even float->bf16 (no NaN inputs here)
  u32 x = __float_as_uint(f);
  u32 r = x + 0x7fffu + ((x >> 16) & 1u);
  return (u16)(r >> 16);
}
static __device__ __forceinline__ float bf2f(u16 v) {
  return __uint_as_float((u32)v << 16);
}

// packed f32x2 -> bf16x2 (RNE), lo = a, hi = b  [T12 recipe]
static __device__ __forceinline__ u32 cvtpk(float a, float b) {
  u32 r;
  asm("v_cvt_pk_bf16_f32 %0, %1, %2" : "=v"(r) : "v"(a), "v"(b));
  return r;
}

// async global->LDS, 16B per lane; LDS dest must be linear (base + lane*16)
static __device__ __forceinline__ void gl_lds16(const void* g, void* l) {
  __builtin_amdgcn_global_load_lds((const __attribute__((address_space(1))) void*)g,
                                   (__attribute__((address_space(3))) void*)l, 16, 0, 0);
}

// ---------------- fused prep: per-token absmax+quant  ||  |w| partial sums --
__global__ __launch_bounds__(256) void k_prep(const float* __restrict__ x, s8* __restrict__ xq,
                                              float* __restrict__ amax,
                                              const float* __restrict__ w0, const float* __restrict__ w1,
                                              const float* __restrict__ w2, const float* __restrict__ w3,
                                              double* __restrict__ part) {
  __shared__ double redd[256];
  __shared__ float  redf[4];
  int t = threadIdx.x;
  if (blockIdx.x < MM) {
    int row = blockIdx.x;
    const float* p = x + (size_t)row * DD + t * 8;
    float4 v0 = *(const float4*)(p);
    float4 v1 = *(const float4*)(p + 4);
    float f[8];
    f[0] = v0.x; f[1] = v0.y; f[2] = v0.z; f[3] = v0.w;
    f[4] = v1.x; f[5] = v1.y; f[6] = v1.z; f[7] = v1.w;
    float m = 0.f;
    #pragma unroll
    for (int i = 0; i < 8; i++) m = fmaxf(m, fabsf(f[i]));
    m = fmaxf(m, __shfl_xor(m, 1));  m = fmaxf(m, __shfl_xor(m, 2));
    m = fmaxf(m, __shfl_xor(m, 4));  m = fmaxf(m, __shfl_xor(m, 8));
    m = fmaxf(m, __shfl_xor(m, 16)); m = fmaxf(m, __shfl_xor(m, 32));
    if ((t & 63) == 0) redf[t >> 6] = m;
    __syncthreads();
    m = fmaxf(fmaxf(redf[0], redf[1]), fmaxf(redf[2], redf[3]));
    m = fmaxf(m, 1e-8f);               // clip(amax, 1e-8)
    if (t == 0) amax[row] = m;
    float s = 127.0f / m;              // matches ref: QMAX / a_max
    s8 o[8];
    #pragma unroll
    for (int i = 0; i < 8; i++)
      o[i] = (s8)(int)fminf(127.f, fmaxf(-127.f, rintf(f[i] * s)));
    *(uint2*)(xq + (size_t)row * DD + t * 8) = *(const uint2*)o;
  } else {
    int idx = blockIdx.x - MM;         // 0..1023
    int m = idx >> 8, blk = idx & 255;
    const float* w = (m == 0) ? w0 : (m == 1) ? w1 : (m == 2) ? w2 : w3;
    const float* p = w + (size_t)blk * 16384;
    double s = 0.0;
    for (int i = t * 4; i < 16384; i += 1024) {
      float4 v = *(const float4*)(p + i);
      s += (double)fabsf(v.x) + (double)fabsf(v.y) + (double)fabsf(v.z) + (double)fabsf(v.w);
    }
    redd[t] = s;
    __syncthreads();
    for (int off = 128; off > 0; off >>= 1) {
      if (t < off) redd[t] += redd[t + off];
      __syncthreads();
    }
    if (t == 0) part[m * 256 + blk] = redd[0];
  }
}

__global__ void k_wscale_final(const double* __restrict__ part, float* __restrict__ scales) {
  int m = threadIdx.x;
  if (m < 4) {
    double s = 0.0;
    for (int i = 0; i < 256; i++) s += part[m * 256 + i];
    float v = (float)(s * (1.0 / 4194304.0));   // /(D*D), power of 2: exact
    scales[m] = fmaxf(v, 1e-6f);
  }
}

// ---------------- ternary weight quant -> int8 ------------------------------
__global__ void k_wquant(const float* __restrict__ w0, const float* __restrict__ w1,
                         const float* __restrict__ w2, const float* __restrict__ w3,
                         s8* __restrict__ wq, const float* __restrict__ scales) {
  int m = blockIdx.y;
  const float* w = (m == 0) ? w0 : (m == 1) ? w1 : (m == 2) ? w2 : w3;
  float ws = scales[m];
  size_t i = ((size_t)blockIdx.x * 256 + threadIdx.x) * 4;
  float4 v = *(const float4*)(w + i);
  s8 o[4];
  o[0] = (s8)(int)fminf(1.f, fmaxf(-1.f, rintf(v.x / ws)));
  o[1] = (s8)(int)fminf(1.f, fmaxf(-1.f, rintf(v.y / ws)));
  o[2] = (s8)(int)fminf(1.f, fmaxf(-1.f, rintf(v.z / ws)));
  o[3] = (s8)(int)fminf(1.f, fmaxf(-1.f, rintf(v.w / ws)));
  *(int*)(wq + (size_t)m * DD * DD + i) = *(const int*)o;
}

// ---------------- int8 MFMA GEMM: 4-phase split of the r12 schedule ---------
// Staging ledger IDENTICAL to the verified 2-phase version (same per-wave
// issue order A(t+1), B1(t+1), B0(t+2); same tile-end vmcnt(NJ) counting;
// B0(t+2) still issued only after the last cur-half0 reader). Only the
// granularity changed: 4 phases x {small ds_read batch -> 8*NJ/4*NJ MFMA},
// splitting each MFMA-16 cluster by ks for finer cross-wave overlap.
template<bool OB, int NBNL, int BN>
__global__ __launch_bounds__(512) void k_gemm(const s8* __restrict__ A, const s8* __restrict__ Bw,
                                              const float* __restrict__ amax,
                                              const float* __restrict__ scales, int sbase,
                                              void* __restrict__ outv) {
  constexpr int NJ = BN / 128;
  __shared__ alignas(16) u8 Asm[2][128 * 128];
  __shared__ alignas(16) u8 Bsm[2][BN * 128];
  int id = blockIdx.x;
  int xcd = id & 7, kk = id >> 3;
  int bm = kk & 31, bn = xcd * NBNL + (kk >> 5);   // bm-inner: B-panel L2-resident per XCD
  int t = threadIdx.x, w = t >> 6, l = t & 63;
  int wr = w >> 2, wc = w & 3;                     // 2M x 4N waves
  int l15 = l & 15, lh = l >> 4;
  int r0 = t >> 3;                                 // staging row (i=0); i=1 row = r0+64
  int c0 = ((t & 7) ^ (r0 & 7)) * 16;              // pre-swizzled source byte col
  const s8* Ab = A  + (size_t)(bm * 128) * DD;
  const s8* Bb = Bw + (size_t)(bn * BN) * DD;

  auto STG_A = [&](int tt) {
    u8* d_ = &Asm[tt & 1][0];
    gl_lds16(Ab + (size_t)r0 * DD + tt * 128 + c0,        d_ + t * 16);
    gl_lds16(Ab + (size_t)(r0 + 64) * DD + tt * 128 + c0, d_ + (512 + t) * 16);
  };
  auto STG_B = [&](int tt, int h_) {
    u8* d_ = &Bsm[tt & 1][(size_t)h_ * (BN / 2) * 128];
    #pragma unroll
    for (int jj = 0; jj < NJ; jj++)
      gl_lds16(Bb + (size_t)(h_ * (BN / 2) + jj * 64 + r0) * DD + tt * 128 + c0,
               d_ + (jj * 512 + t) * 16);
  };

  i32x4 acc[4][2 * NJ] = {};
  STG_A(0); STG_B(0, 0); STG_B(0, 1); STG_B(1, 0);
  if constexpr (NJ == 2) asm volatile("s_waitcnt vmcnt(2)" ::: "memory");
  else                   asm volatile("s_waitcnt vmcnt(1)" ::: "memory");
  asm volatile("s_barrier" ::: "memory");
  for (int kb = 0; kb < 16; kb++) {
    int b = kb & 1;
    const u8* Ac = &Asm[b][0];
    const u8* Bc = &Bsm[b][0];
    i32x4 af0[4], af1[4], bf0[NJ], bf1[NJ], bg0[NJ], bg1[NJ];
    // ---- P1: A ks0 + B-half0 ks0 ; stage A(t+1) ----
    #pragma unroll
    for (int i = 0; i < 4; i++)
      af0[i] = *(const i32x4*)(Ac + (wr * 64 + i * 16 + l15) * 128 + ((lh ^ (l15 & 7)) * 16));
    #pragma unroll
    for (int j = 0; j < NJ; j++)
      bf0[j] = *(const i32x4*)(Bc + ((wc + 4 * j) * 16 + l15) * 128 + ((lh ^ (l15 & 7)) * 16));
    if (kb + 1 < 16) STG_A(kb + 1);
    asm volatile("s_barrier" ::: "memory");
    asm volatile("s_waitcnt lgkmcnt(0)" ::: "memory");
    __builtin_amdgcn_sched_barrier(0);
    __builtin_amdgcn_s_setprio(1);
    #pragma unroll
    for (int i = 0; i < 4; i++)
      #pragma unroll
      for (int j = 0; j < NJ; j++)
        acc[i][j] = MFMAI8(af0[i], bf0[j], acc[i][j]);
    __builtin_amdgcn_s_setprio(0);
    asm volatile("s_barrier" ::: "memory");
    // ---- P2: A ks1 + B-half0 ks1 ; stage B1(t+1) ----
    #pragma unroll
    for (int i = 0; i < 4; i++)
      af1[i] = *(const i32x4*)(Ac + (wr * 64 + i * 16 + l15) * 128 + (((4 + lh) ^ (l15 & 7)) * 16));
    #pragma unroll
    for (int j = 0; j < NJ; j++)
      bf1[j] = *(const i32x4*)(Bc + ((wc + 4 * j) * 16 + l15) * 128 + (((4 + lh) ^ (l15 & 7)) * 16));
    if (kb + 1 < 16) STG_B(kb + 1, 1);
    asm volatile("s_barrier" ::: "memory");
    asm volatile("s_waitcnt lgkmcnt(0)" ::: "memory");
    __builtin_amdgcn_sched_barrier(0);
    __builtin_amdgcn_s_setprio(1);
    #pragma unroll
    for (int i = 0; i < 4; i++)
      #pragma unroll
      for (int j = 0; j < NJ; j++)
        acc[i][j] = MFMAI8(af1[i], bf1[j], acc[i][j]);
    __builtin_amdgcn_s_setprio(0);
    asm volatile("s_barrier" ::: "memory");
    // ---- P3: B-half1 ks0 (cur-half0 reads now complete) ----
    #pragma unroll
    for (int j = 0; j < NJ; j++)
      bg0[j] = *(const i32x4*)(Bc + ((wc + 4 * (NJ + j)) * 16 + l15) * 128 + ((lh ^ (l15 & 7)) * 16));
    asm volatile("s_barrier" ::: "memory");
    asm volatile("s_waitcnt lgkmcnt(0)" ::: "memory");
    __builtin_amdgcn_sched_barrier(0);
    __builtin_amdgcn_s_setprio(1);
    #pragma unroll
    for (int i = 0; i < 4; i++)
      #pragma unroll
      for (int j = 0; j < NJ; j++)
        acc[i][NJ + j] = MFMAI8(af0[i], bg0[j], acc[i][NJ + j]);
    __builtin_amdgcn_s_setprio(0);
    asm volatile("s_barrier" ::: "memory");
    // ---- P4: B-half1 ks1 ; stage B0(t+2) into cur buf half0 ----
    #pragma unroll
    for (int j = 0; j < NJ; j++)
      bg1[j] = *(const i32x4*)(Bc + ((wc + 4 * (NJ + j)) * 16 + l15) * 128 + (((4 + lh) ^ (l15 & 7)) * 16));
    if (kb + 2 < 16) STG_B(kb + 2, 0);
    asm volatile("s_barrier" ::: "memory");
    asm volatile("s_waitcnt lgkmcnt(0)" ::: "memory");
    __builtin_amdgcn_sched_barrier(0);
    __builtin_amdgcn_s_setprio(1);
    #pragma unroll
    for (int i = 0; i < 4; i++)
      #pragma unroll
      for (int j = 0; j < NJ; j++)
        acc[i][NJ + j] = MFMAI8(af1[i], bg1[j], acc[i][NJ + j]);
    __builtin_amdgcn_s_setprio(0);
    if (kb < 14) {
      if constexpr (NJ == 2) asm volatile("s_waitcnt vmcnt(2)" ::: "memory");
      else                   asm volatile("s_waitcnt vmcnt(1)" ::: "memory");
      asm volatile("s_barrier" ::: "memory");
    } else if (kb == 14) {
      asm volatile("s_waitcnt vmcnt(0)" ::: "memory");
      asm volatile("s_barrier" ::: "memory");
    }
  }
  int mz = OB ? (bn >> 3) : 0;                      // OB path assumes BN=256
  int lcol0 = OB ? ((bn & 7) * 256) : (bn * BN);
  float wsc = scales[sbase + mz];
  u16*   outb = (u16*)outv + (size_t)mz * MM * DD;
  float* outf = (float*)outv;
  #pragma unroll
  for (int i = 0; i < 4; i++) {
    int row0 = bm * 128 + wr * 64 + i * 16 + lh * 4;
    #pragma unroll
    for (int r = 0; r < 4; r++) {
      float sc = (wsc * amax[row0 + r]) / 127.0f;
      #pragma unroll
      for (int j = 0; j < 2 * NJ; j++) {
        int col = lcol0 + (wc + 4 * j) * 16 + l15;
        float y = (float)acc[i][j][r] * sc;
        if (OB) outb[(size_t)(row0 + r) * DD + col] = f2bf(y);
        else    outf[(size_t)(row0 + r) * DD + col] = y;
      }
    }
  }
}

// ---------------- V transpose: v[b*S+s][h*128+d] -> vt[(b*16+h)*128+d][s] ---
__global__ __launch_bounds__(256) void k_vtrans(const u16* __restrict__ v, u16* __restrict__ vt) {
  __shared__ u16 tile[64][72];
  int sb = blockIdx.x;           // S/64
  int db = blockIdx.y;           // HD/64
  int bh = blockIdx.z;           // B*H
  int b = bh >> 4, h = bh & 15;
  int t = threadIdx.x;
  int ls = t >> 2, ld0 = (t & 3) * 16;
  const u16* src = v + (size_t)(b * SS + sb * 64 + ls) * DD + h * HDD + db * 64 + ld0;
  *(int4*)(&tile[ls][ld0])     = *(const int4*)(src);
  *(int4*)(&tile[ls][ld0 + 8]) = *(const int4*)(src + 8);
  __syncthreads();
  int d = t >> 2, s0 = (t & 3) * 16;
  u16 tmp[16];
  #pragma unroll
  for (int k = 0; k < 16; k++) tmp[k] = tile[s0 + k][d];
  u16* dst = vt + (size_t)((bh * HDD) + db * 64 + d) * SS + sb * 64 + s0;
  *(int4*)(dst)     = *(const int4*)(tmp);
  *(int4*)(dst + 8) = *(const int4*)(tmp + 8);
}

// ---------------- causal flash attention: 8-warp parity split-KV (FROZEN r18)
__global__ __launch_bounds__(512) void k_attn(const u16* __restrict__ Q, const u16* __restrict__ K,
                                              const u16* __restrict__ VT,
                                              u16* __restrict__ O0, u16* __restrict__ O1,
                                              float2* __restrict__ ml) {
  __shared__ alignas(16) u16 Ks[2][64 * 128];  // [kv][d]  256B rows, 16B slots XOR (row&15)
  __shared__ alignas(16) u16 Vs[2][128 * 64];  // [d][kv]  128B rows, 16B slots XOR (row&7)
  __shared__ alignas(16) u16 Ps[8 * 32 * 64];  // per-warp P[q][kv], 16B slots XOR (row&7)
  int id = blockIdx.x;
  int bh = (id & 7) * 4 + ((id >> 3) & 3);     // 4 heads per XCD (K+V^T L2-resident)
  int rest = id >> 5;                          // 0..7
  int pr = rest & 3;                           // q-pair index (256-row q-tiles)
  int par = rest >> 2;                         // K-parity 0/1
  int b = bh >> 4, h = bh & 15;
  int t = threadIdx.x, w = t >> 6, l = t & 63; // w in 0..7
  int l31 = l & 31, hi = l >> 5;
  int l15 = l & 15, lh = l >> 4;               // 16x16 roles (PV)
  size_t base = (size_t)(b * SS) * DD + h * HDD;
  const u16* vtb = VT + (size_t)bh * HDD * SS;
  u16* Ptw = Ps + w * 2048;
  u16* Opar = par ? O1 : O0;
  const float sc2 = 0.12751944557270094f;      // log2(e)/sqrt(128)
  // staging maps: 512 threads cover 1024 16B slots per tile in 2 instrs each
  int ksr[2], kso[2], vsr[2], vso[2];
  #pragma unroll
  for (int i = 0; i < 2; i++) {
    int s = i * 512 + t;
    ksr[i] = s >> 4; kso[i] = ((s & 15) ^ (ksr[i] & 15)) * 8;
    vsr[i] = s >> 3; vso[i] = ((s & 7) ^ (vsr[i] & 7)) * 8;
  }

#define ASTAGE(kb_, bf_) do {                                                           \
    _Pragma("unroll")                                                                   \
    for (int i_ = 0; i_ < 2; i_++)                                                      \
      gl_lds16(K + base + (size_t)((kb_) * 64 + ksr[i_]) * DD + kso[i_],                \
               &Ks[bf_][(i_ * 512 + t) * 8]);                                           \
    _Pragma("unroll")                                                                   \
    for (int i_ = 0; i_ < 2; i_++)                                                      \
      gl_lds16(vtb + (size_t)vsr[i_] * SS + (kb_) * 64 + vso[i_],                       \
               &Vs[bf_][(i_ * 512 + t) * 8]);                                           \
  } while (0)

  for (int half = 0; half < 2; half++) {
    int qt = half ? (7 - pr) : pr;             // 256-row q-tile index
    int qrow = qt * 256 + w * 32 + l31;
    bf16x8 qf[8];
    #pragma unroll
    for (int kt = 0; kt < 8; kt++)
      qf[kt] = *(const bf16x8*)(Q + base + (size_t)qrow * DD + kt * 16 + hi * 8);
    f32x4 cacc[2][8] = {};
    float mrun = -INFINITY, lrun = 0.f;
    int nkb = 4 * qt + 4;                      // K-tiles covering this q-tile
    ASTAGE(par, 0);
    asm volatile("s_waitcnt vmcnt(0)" ::: "memory");
    asm volatile("s_barrier" ::: "memory");
    int it = 0;
    for (int kb = par; kb < nkb; kb += 2, it++) {
      int cur = it & 1;
      if (kb + 2 < nkb) ASTAGE(kb + 2, cur ^ 1);  // in flight during compute(kb)
      const u16* Kc = &Ks[cur][0];
      const u16* Vc = &Vs[cur][0];
      // ---- S^T = K.Q^T : lane owns q-row (col=l31); kv via regs & hi ----
      f32x16 c0 = {}, c1 = {};
      #pragma unroll
      for (int kt = 0; kt < 8; kt++) {
        int sl = (((kt * 2 + hi) ^ (l31 & 15)) * 8);
        bf16x8 kf0 = *(const bf16x8*)(Kc + l31 * 128 + sl);
        bf16x8 kf1 = *(const bf16x8*)(Kc + (32 + l31) * 128 + sl);
        c0 = MFMA32(kf0, qf[kt], c0);
        c1 = MFMA32(kf1, qf[kt], c1);
      }
      if (kb >= 4 * qt) {   // causal mask (diagonal/future tiles only)
        #pragma unroll
        for (int rg = 0; rg < 16; rg++) {
          int kv0 = kb * 64 + (rg & 3) + 8 * (rg >> 2) + 4 * hi;
          if (kv0 > qrow)      c0[rg] = -1e30f;
          if (kv0 + 32 > qrow) c1[rg] = -1e30f;
        }
      }
      // ---- in-register online softmax (exp2-folded) ----
      float ta[16];
      #pragma unroll
      for (int rg = 0; rg < 16; rg++) ta[rg] = fmaxf(c0[rg], c1[rg]);
      #pragma unroll
      for (int off = 8; off > 0; off >>= 1)
        #pragma unroll
        for (int rg = 0; rg < 8; rg++)
          if (rg < off) ta[rg] = fmaxf(ta[rg], ta[rg + off]);
      float pmax = fmaxf(ta[0], __shfl_xor(ta[0], 32));
      if (__any(pmax - mrun > 90.50967f)) {        // defer-max THR=8 (exp units)
        float mnew = fmaxf(mrun, pmax);
        float alpha = __builtin_amdgcn_exp2f((mrun - mnew) * sc2);
        lrun *= alpha;
        #pragma unroll
        for (int m16 = 0; m16 < 2; m16++)
          #pragma unroll
          for (int r = 0; r < 4; r++) {
            float ar = __shfl(alpha, m16 * 16 + lh * 4 + r);
            #pragma unroll
            for (int n2 = 0; n2 < 8; n2++) cacc[m16][n2][r] *= ar;
          }
        mrun = mnew;
      }
      float msc2 = mrun * sc2;
      float ts[16];
      #pragma unroll
      for (int rg = 0; rg < 16; rg++) {
        float p0 = __builtin_amdgcn_exp2f(fmaf(c0[rg], sc2, -msc2)); c0[rg] = p0;
        float p1 = __builtin_amdgcn_exp2f(fmaf(c1[rg], sc2, -msc2)); c1[rg] = p1;
        ts[rg] = p0 + p1;
      }
      #pragma unroll
      for (int off = 8; off > 0; off >>= 1)
        #pragma unroll
        for (int rg = 0; rg < 8; rg++)
          if (rg < off) ts[rg] += ts[rg + off];
      lrun += ts[0] + __shfl_xor(ts[0], 32);
      // ---- P -> per-warp LDS (cvt_pk packing) ----
      #pragma unroll
      for (int q4 = 0; q4 < 4; q4++) {
        uint2 pk0, pk1;
        pk0.x = cvtpk(c0[4 * q4 + 0], c0[4 * q4 + 1]);
        pk0.y = cvtpk(c0[4 * q4 + 2], c0[4 * q4 + 3]);
        pk1.x = cvtpk(c1[4 * q4 + 0], c1[4 * q4 + 1]);
        pk1.y = cvtpk(c1[4 * q4 + 2], c1[4 * q4 + 3]);
        *(uint2*)(Ptw + l31 * 64 + ((q4 ^ (l31 & 7)) * 8 + 4 * hi))       = pk0;
        *(uint2*)(Ptw + l31 * 64 + (((4 + q4) ^ (l31 & 7)) * 8 + 4 * hi)) = pk1;
      }
      // ---- PV (16x16x32): O[q][d] += P.V ----
      #pragma unroll
      for (int ks = 0; ks < 2; ks++) {
        int so = ((ks * 4 + lh) ^ (l15 & 7)) * 8;
        bf16x8 pf0 = *(const bf16x8*)(Ptw + (l15) * 64 + so);
        bf16x8 pf1 = *(const bf16x8*)(Ptw + (16 + l15) * 64 + so);
        #pragma unroll
        for (int n2 = 0; n2 < 8; n2++) {
          bf16x8 vf = *(const bf16x8*)(Vc + (n2 * 16 + l15) * 64 + so);
          cacc[0][n2] = MFMA(pf0, vf, cacc[0][n2]);
          cacc[1][n2] = MFMA(pf1, vf, cacc[1][n2]);
        }
      }
      // ---- post-compute drain: stage(kb+2) landed + all warps done(kb) ----
      asm volatile("s_waitcnt vmcnt(0)" ::: "memory");
      asm volatile("s_barrier" ::: "memory");
    }
    // ---- epilogue: UNNORMALIZED partial O (bf16) + per-row (m,l) ----
    u16* Ob = Opar + (size_t)(bh * 2048 + qt * 256) * 128;
    #pragma unroll
    for (int m16 = 0; m16 < 2; m16++)
      #pragma unroll
      for (int r = 0; r < 4; r++) {
        u16* op = Ob + (size_t)(w * 32 + m16 * 16 + lh * 4 + r) * 128;
        #pragma unroll
        for (int n2 = 0; n2 < 8; n2++)
          op[n2 * 16 + l15] = f2bf(cacc[m16][n2][r]);
      }
    if (l < 32) {
      int uid = bh * 2048 + qt * 256 + w * 32 + l31;
      ml[(size_t)par * 65536 + uid] = make_float2(mrun, lrun);
    }
  }
#undef ASTAGE
}

// ---------------- fused combine + row-quant: parities -> int8 ctx_q ---------
__global__ __launch_bounds__(256) void k_combine_quant(const u16* __restrict__ O0, const u16* __restrict__ O1,
                                                       const float2* __restrict__ ml,
                                                       s8* __restrict__ xq, float* __restrict__ amax) {
  const float sc2 = 0.12751944557270094f;      // log2(e)/sqrt(128)
  int r = blockIdx.x;                          // global token row 0..4095
  int b = r >> 11, qrow = r & 2047;
  int t = threadIdx.x;
  int col = t * 8;
  int h = col >> 7, d0 = col & 127;
  int unit = (b * 16 + h) * 2048 + qrow;
  float2 m0 = ml[unit];
  float2 m1 = ml[65536 + unit];
  float mx = fmaxf(m0.x, m1.x);
  float w0 = __builtin_amdgcn_exp2f((m0.x - mx) * sc2);
  float w1 = __builtin_amdgcn_exp2f((m1.x - mx) * sc2);
  float linv = 1.0f / (w0 * m0.y + w1 * m1.y);
  w0 *= linv; w1 *= linv;
  int4 a  = *(const int4*)(O0 + (size_t)unit * 128 + d0);
  int4 bb = *(const int4*)(O1 + (size_t)unit * 128 + d0);
  const u16* pa = (const u16*)&a;
  const u16* pb = (const u16*)&bb;
  float f[8];
  #pragma unroll
  for (int i = 0; i < 8; i++) f[i] = w0 * bf2f(pa[i]) + w1 * bf2f(pb[i]);
  float m = 0.f;
  #pragma unroll
  for (int i = 0; i < 8; i++) m = fmaxf(m, fabsf(f[i]));
  m = fmaxf(m, __shfl_xor(m, 1));  m = fmaxf(m, __shfl_xor(m, 2));
  m = fmaxf(m, __shfl_xor(m, 4));  m = fmaxf(m, __shfl_xor(m, 8));
  m = fmaxf(m, __shfl_xor(m, 16)); m = fmaxf(m, __shfl_xor(m, 32));
  __shared__ float red[4];
  if ((t & 63) == 0) red[t >> 6] = m;
  __syncthreads();
  m = fmaxf(fmaxf(red[0], red[1]), fmaxf(red[2], red[3]));
  m = fmaxf(m, 1e-8f);                 // clip(amax, 1e-8)
  if (t == 0) amax[r] = m;
  float s = 127.0f / m;                // matches ref: QMAX / a_max
  s8 o[8];
  #pragma unroll
  for (int i = 0; i < 8; i++)
    o[i] = (s8)(int)fminf(127.f, fmaxf(-127.f, rintf(f[i] * s)));
  *(uint2*)(xq + (size_t)r * DD + col) = *(const uint2*)o;
}

// ---------------- launch ----------------------------------------------------
// ws layout (bytes), within the proven 134,348,800 extent:
//   0        scales (4 f32)        256      partials (1024 f64)
//   16384    amax_x                49152    amax_ctx
//   131072   w_q int8 (4 x D*D)  = 16,777,216   (ends 16,908,288)
//   16908288 ml float2 x 2 x 65536 = 1,048,576
//   33685504 x_q int8 (M*D)      =  8,388,608   (region reused as V^T bf16, then ctx_q)
//   50462720 q bf16 | 67239936 k | 84017152 v   (16,777,216 each)
//   84017152 O0 partial bf16 (reuses dead v region after vtrans)
//   117571584 O1 partial bf16    = 16,777,216   (ends 134,348,800)
extern "C" void kernel_launch(void* const* d_in, const int* in_sizes, int n_in,
                              void* d_out, int out_size, void* d_ws, size_t ws_size,
                              hipStream_t stream) {
  const float* x  = (const float*)d_in[0];
  const float* wq = (const float*)d_in[1];
  const float* wk = (const float*)d_in[2];
  const float* wv = (const float*)d_in[3];
  const float* wo = (const float*)d_in[4];
  char* ws = (char*)d_ws;
  float*  scales = (float*)(ws + 0);
  double* part   = (double*)(ws + 256);
  float*  amaxx  = (float*)(ws + 16384);
  float*  amaxc  = (float*)(ws + 49152);
  s8*     wqq    = (s8*)(ws + 131072);
  float2* ml     = (float2*)(ws + 16908288);
  s8*     xq     = (s8*)(ws + 33685504);    // int8 activations; region reused as V^T, ctx_q
  u16*    vt16   = (u16*)(ws + 33685504);
  u16*    qb     = (u16*)(ws + 50462720);
  u16*    kb     = (u16*)(ws + 67239936);
  u16*    vb     = (u16*)(ws + 84017152);
  u16*    O0     = (u16*)(ws + 84017152);   // reuses dead v region
  u16*    O1     = (u16*)(ws + 117571584);
  (void)in_sizes; (void)n_in; (void)out_size; (void)ws_size;

  // fused: rowquant(x) || weight-|.| partial sums  (disjoint buffers)
  k_prep<<<MM + 1024, 256, 0, stream>>>(x, xq, amaxx, wq, wk, wv, wo, part);
  k_wscale_final<<<1, 64, 0, stream>>>(part, scales);
  k_wquant<<<dim3(4096, 4), 256, 0, stream>>>(wq, wk, wv, wo, wqq, scales);
  k_gemm<true, 3, 256><<<768, 512, 0, stream>>>(xq, wqq, amaxx, scales, 0, (void*)qb);
  k_vtrans<<<dim3(32, 2, 32), 256, 0, stream>>>(vb, vt16);
  k_attn<<<256, 512, 0, stream>>>(qb, kb, vt16, O0, O1, ml);
  // fused combine + row-quant straight to int8 (ctx bf16 round-trip removed)
  k_combine_quant<<<MM, 256, 0, stream>>>(O0, O1, ml, xq, amaxc);
  k_gemm<false, 2, 128><<<512, 512, 0, stream>>>(xq, wqq + (size_t)3 * DD * DD, amaxc, scales, 3, d_out);
}

// Round 21
// 198.087 us; speedup vs baseline: 1.0765x; 1.0765x over previous
//
#include <hip/hip_runtime.h>
#include <hip/hip_bf16.h>
#include <cstdint>
#include <cstddef>

// BitNet b1.58 attention block: B=2 S=2048 D=2048 H=16 HD=128.
// Projections via int8 MFMA (exact: int8 x ternary, |acc| <= 2048*127 < 2^24);
// attention via bf16 MFMA, parity-split-KV with a fused combine+quant pass.

#define BB 2
#define SS 2048
#define DD 2048
#define HH 16
#define HDD 128
#define MM (BB*SS)   // 4096 token rows

typedef __attribute__((ext_vector_type(8))) short bf16x8;
typedef __attribute__((ext_vector_type(4))) float f32x4;
typedef __attribute__((ext_vector_type(16))) float f32x16;
typedef __attribute__((ext_vector_type(4))) int   i32x4;
typedef unsigned short u16;
typedef unsigned int   u32;
typedef unsigned char  u8;
typedef signed char    s8;

#define MFMA(a,b,c)   __builtin_amdgcn_mfma_f32_16x16x32_bf16(a,b,c,0,0,0)
#define MFMA32(a,b,c) __builtin_amdgcn_mfma_f32_32x32x16_bf16(a,b,c,0,0,0)
#define MFMAI8(a,b,c) __builtin_amdgcn_mfma_i32_16x16x64_i8(a,b,c,0,0,0)

static __device__ __forceinline__ u16 f2bf(float f) {
  // round-to-nearest-even float->bf16 (no NaN inputs here)
  u32 x = __float_as_uint(f);
  u32 r = x + 0x7fffu + ((x >> 16) & 1u);
  return (u16)(r >> 16);
}
static __device__ __forceinline__ float bf2f(u16 v) {
  return __uint_as_float((u32)v << 16);
}

// packed f32x2 -> bf16x2 (RNE), lo = a, hi = b  [T12 recipe]
static __device__ __forceinline__ u32 cvtpk(float a, float b) {
  u32 r;
  asm("v_cvt_pk_bf16_f32 %0, %1, %2" : "=v"(r) : "v"(a), "v"(b));
  return r;
}

// async global->LDS, 16B per lane; LDS dest must be linear (base + lane*16)
static __device__ __forceinline__ void gl_lds16(const void* g, void* l) {
  __builtin_amdgcn_global_load_lds((const __attribute__((address_space(1))) void*)g,
                                   (__attribute__((address_space(3))) void*)l, 16, 0, 0);
}

// ---------------- fused prep: per-token absmax+quant  ||  |w| partial sums --
__global__ __launch_bounds__(256) void k_prep(const float* __restrict__ x, s8* __restrict__ xq,
                                              float* __restrict__ amax,
                                              const float* __restrict__ w0, const float* __restrict__ w1,
                                              const float* __restrict__ w2, const float* __restrict__ w3,
                                              double* __restrict__ part) {
  __shared__ double redd[256];
  __shared__ float  redf[4];
  int t = threadIdx.x;
  if (blockIdx.x < MM) {
    int row = blockIdx.x;
    const float* p = x + (size_t)row * DD + t * 8;
    float4 v0 = *(const float4*)(p);
    float4 v1 = *(const float4*)(p + 4);
    float f[8];
    f[0] = v0.x; f[1] = v0.y; f[2] = v0.z; f[3] = v0.w;
    f[4] = v1.x; f[5] = v1.y; f[6] = v1.z; f[7] = v1.w;
    float m = 0.f;
    #pragma unroll
    for (int i = 0; i < 8; i++) m = fmaxf(m, fabsf(f[i]));
    m = fmaxf(m, __shfl_xor(m, 1));  m = fmaxf(m, __shfl_xor(m, 2));
    m = fmaxf(m, __shfl_xor(m, 4));  m = fmaxf(m, __shfl_xor(m, 8));
    m = fmaxf(m, __shfl_xor(m, 16)); m = fmaxf(m, __shfl_xor(m, 32));
    if ((t & 63) == 0) redf[t >> 6] = m;
    __syncthreads();
    m = fmaxf(fmaxf(redf[0], redf[1]), fmaxf(redf[2], redf[3]));
    m = fmaxf(m, 1e-8f);               // clip(amax, 1e-8)
    if (t == 0) amax[row] = m;
    float s = 127.0f / m;              // matches ref: QMAX / a_max
    s8 o[8];
    #pragma unroll
    for (int i = 0; i < 8; i++)
      o[i] = (s8)(int)fminf(127.f, fmaxf(-127.f, rintf(f[i] * s)));
    *(uint2*)(xq + (size_t)row * DD + t * 8) = *(const uint2*)o;
  } else {
    int idx = blockIdx.x - MM;         // 0..1023
    int m = idx >> 8, blk = idx & 255;
    const float* w = (m == 0) ? w0 : (m == 1) ? w1 : (m == 2) ? w2 : w3;
    const float* p = w + (size_t)blk * 16384;
    double s = 0.0;
    for (int i = t * 4; i < 16384; i += 1024) {
      float4 v = *(const float4*)(p + i);
      s += (double)fabsf(v.x) + (double)fabsf(v.y) + (double)fabsf(v.z) + (double)fabsf(v.w);
    }
    redd[t] = s;
    __syncthreads();
    for (int off = 128; off > 0; off >>= 1) {
      if (t < off) redd[t] += redd[t + off];
      __syncthreads();
    }
    if (t == 0) part[m * 256 + blk] = redd[0];
  }
}

__global__ void k_wscale_final(const double* __restrict__ part, float* __restrict__ scales) {
  int m = threadIdx.x;
  if (m < 4) {
    double s = 0.0;
    for (int i = 0; i < 256; i++) s += part[m * 256 + i];
    float v = (float)(s * (1.0 / 4194304.0));   // /(D*D), power of 2: exact
    scales[m] = fmaxf(v, 1e-6f);
  }
}

// ---------------- ternary weight quant -> int8 ------------------------------
__global__ void k_wquant(const float* __restrict__ w0, const float* __restrict__ w1,
                         const float* __restrict__ w2, const float* __restrict__ w3,
                         s8* __restrict__ wq, const float* __restrict__ scales) {
  int m = blockIdx.y;
  const float* w = (m == 0) ? w0 : (m == 1) ? w1 : (m == 2) ? w2 : w3;
  float ws = scales[m];
  size_t i = ((size_t)blockIdx.x * 256 + threadIdx.x) * 4;
  float4 v = *(const float4*)(w + i);
  s8 o[4];
  o[0] = (s8)(int)fminf(1.f, fmaxf(-1.f, rintf(v.x / ws)));
  o[1] = (s8)(int)fminf(1.f, fmaxf(-1.f, rintf(v.y / ws)));
  o[2] = (s8)(int)fminf(1.f, fmaxf(-1.f, rintf(v.z / ws)));
  o[3] = (s8)(int)fminf(1.f, fmaxf(-1.f, rintf(v.w / ws)));
  *(int*)(wq + (size_t)m * DD * DD + i) = *(const int*)o;
}

// ---------------- int8 MFMA GEMM (r12/r19-verified 2-phase schedule) --------
template<bool OB, int NBNL, int BN>
__global__ __launch_bounds__(512) void k_gemm(const s8* __restrict__ A, const s8* __restrict__ Bw,
                                              const float* __restrict__ amax,
                                              const float* __restrict__ scales, int sbase,
                                              void* __restrict__ outv) {
  constexpr int NJ = BN / 128;
  __shared__ alignas(16) u8 Asm[2][128 * 128];
  __shared__ alignas(16) u8 Bsm[2][BN * 128];
  int id = blockIdx.x;
  int xcd = id & 7, kk = id >> 3;
  int bm = kk & 31, bn = xcd * NBNL + (kk >> 5);   // bm-inner: B-panel L2-resident per XCD
  int t = threadIdx.x, w = t >> 6, l = t & 63;
  int wr = w >> 2, wc = w & 3;                     // 2M x 4N waves
  int l15 = l & 15, lh = l >> 4;
  int r0 = t >> 3;                                 // staging row (i=0); i=1 row = r0+64
  int c0 = ((t & 7) ^ (r0 & 7)) * 16;              // pre-swizzled source byte col
  const s8* Ab = A  + (size_t)(bm * 128) * DD;
  const s8* Bb = Bw + (size_t)(bn * BN) * DD;

  auto STG_A = [&](int tt) {
    u8* d_ = &Asm[tt & 1][0];
    gl_lds16(Ab + (size_t)r0 * DD + tt * 128 + c0,        d_ + t * 16);
    gl_lds16(Ab + (size_t)(r0 + 64) * DD + tt * 128 + c0, d_ + (512 + t) * 16);
  };
  auto STG_B = [&](int tt, int h_) {
    u8* d_ = &Bsm[tt & 1][(size_t)h_ * (BN / 2) * 128];
    #pragma unroll
    for (int jj = 0; jj < NJ; jj++)
      gl_lds16(Bb + (size_t)(h_ * (BN / 2) + jj * 64 + r0) * DD + tt * 128 + c0,
               d_ + (jj * 512 + t) * 16);
  };

  i32x4 acc[4][2 * NJ] = {};
  STG_A(0); STG_B(0, 0); STG_B(0, 1); STG_B(1, 0);
  if constexpr (NJ == 2) asm volatile("s_waitcnt vmcnt(2)" ::: "memory");
  else                   asm volatile("s_waitcnt vmcnt(1)" ::: "memory");
  asm volatile("s_barrier" ::: "memory");
  for (int kb = 0; kb < 16; kb++) {
    int b = kb & 1;
    const u8* Ac = &Asm[b][0];
    const u8* Bc = &Bsm[b][0];
    // ---- phase 1: A frags + B frags (B-half0) ----
    i32x4 af[4][2], bf[NJ][2];
    #pragma unroll
    for (int i = 0; i < 4; i++)
      #pragma unroll
      for (int ks = 0; ks < 2; ks++)
        af[i][ks] = *(const i32x4*)(Ac + (wr * 64 + i * 16 + l15) * 128 + (((ks * 4 + lh) ^ (l15 & 7)) * 16));
    #pragma unroll
    for (int j = 0; j < NJ; j++)
      #pragma unroll
      for (int ks = 0; ks < 2; ks++)
        bf[j][ks] = *(const i32x4*)(Bc + ((wc + 4 * j) * 16 + l15) * 128 + (((ks * 4 + lh) ^ (l15 & 7)) * 16));
    if (kb + 1 < 16) { STG_A(kb + 1); STG_B(kb + 1, 1); }
    asm volatile("s_barrier" ::: "memory");
    asm volatile("s_waitcnt lgkmcnt(0)" ::: "memory");
    __builtin_amdgcn_sched_barrier(0);
    __builtin_amdgcn_s_setprio(1);
    #pragma unroll
    for (int ks = 0; ks < 2; ks++)
      #pragma unroll
      for (int i = 0; i < 4; i++)
        #pragma unroll
        for (int j = 0; j < NJ; j++)
          acc[i][j] = MFMAI8(af[i][ks], bf[j][ks], acc[i][j]);
    __builtin_amdgcn_s_setprio(0);
    asm volatile("s_barrier" ::: "memory");
    // ---- phase 2: B frags (B-half1) ----
    i32x4 bg[NJ][2];
    #pragma unroll
    for (int j = 0; j < NJ; j++)
      #pragma unroll
      for (int ks = 0; ks < 2; ks++)
        bg[j][ks] = *(const i32x4*)(Bc + ((wc + 4 * (NJ + j)) * 16 + l15) * 128 + (((ks * 4 + lh) ^ (l15 & 7)) * 16));
    if (kb + 2 < 16) STG_B(kb + 2, 0);
    asm volatile("s_barrier" ::: "memory");
    asm volatile("s_waitcnt lgkmcnt(0)" ::: "memory");
    __builtin_amdgcn_sched_barrier(0);
    __builtin_amdgcn_s_setprio(1);
    #pragma unroll
    for (int ks = 0; ks < 2; ks++)
      #pragma unroll
      for (int i = 0; i < 4; i++)
        #pragma unroll
        for (int j = 0; j < NJ; j++)
          acc[i][NJ + j] = MFMAI8(af[i][ks], bg[j][ks], acc[i][NJ + j]);
    __builtin_amdgcn_s_setprio(0);
    if (kb < 14) {
      if constexpr (NJ == 2) asm volatile("s_waitcnt vmcnt(2)" ::: "memory");
      else                   asm volatile("s_waitcnt vmcnt(1)" ::: "memory");
      asm volatile("s_barrier" ::: "memory");
    } else if (kb == 14) {
      asm volatile("s_waitcnt vmcnt(0)" ::: "memory");
      asm volatile("s_barrier" ::: "memory");
    }
  }
  int mz = OB ? (bn >> 3) : 0;                      // OB path assumes BN=256
  int lcol0 = OB ? ((bn & 7) * 256) : (bn * BN);
  float wsc = scales[sbase + mz];
  u16*   outb = (u16*)outv + (size_t)mz * MM * DD;
  float* outf = (float*)outv;
  #pragma unroll
  for (int i = 0; i < 4; i++) {
    int row0 = bm * 128 + wr * 64 + i * 16 + lh * 4;
    #pragma unroll
    for (int r = 0; r < 4; r++) {
      float sc = (wsc * amax[row0 + r]) / 127.0f;
      #pragma unroll
      for (int j = 0; j < 2 * NJ; j++) {
        int col = lcol0 + (wc + 4 * j) * 16 + l15;
        float y = (float)acc[i][j][r] * sc;
        if (OB) outb[(size_t)(row0 + r) * DD + col] = f2bf(y);
        else    outf[(size_t)(row0 + r) * DD + col] = y;
      }
    }
  }
}

// ---------------- V transpose: v[b*S+s][h*128+d] -> vt[(b*16+h)*128+d][s] ---
__global__ __launch_bounds__(256) void k_vtrans(const u16* __restrict__ v, u16* __restrict__ vt) {
  __shared__ u16 tile[64][72];
  int sb = blockIdx.x;           // S/64
  int db = blockIdx.y;           // HD/64
  int bh = blockIdx.z;           // B*H
  int b = bh >> 4, h = bh & 15;
  int t = threadIdx.x;
  int ls = t >> 2, ld0 = (t & 3) * 16;
  const u16* src = v + (size_t)(b * SS + sb * 64 + ls) * DD + h * HDD + db * 64 + ld0;
  *(int4*)(&tile[ls][ld0])     = *(const int4*)(src);
  *(int4*)(&tile[ls][ld0 + 8]) = *(const int4*)(src + 8);
  __syncthreads();
  int d = t >> 2, s0 = (t & 3) * 16;
  u16 tmp[16];
  #pragma unroll
  for (int k = 0; k < 16; k++) tmp[k] = tile[s0 + k][d];
  u16* dst = vt + (size_t)((bh * HDD) + db * 64 + d) * SS + sb * 64 + s0;
  *(int4*)(dst)     = *(const int4*)(tmp);
  *(int4*)(dst + 8) = *(const int4*)(tmp + 8);
}

// ---------------- causal flash attention: 8-warp parity split-KV (FROZEN r18)
__global__ __launch_bounds__(512) void k_attn(const u16* __restrict__ Q, const u16* __restrict__ K,
                                              const u16* __restrict__ VT,
                                              u16* __restrict__ O0, u16* __restrict__ O1,
                                              float2* __restrict__ ml) {
  __shared__ alignas(16) u16 Ks[2][64 * 128];  // [kv][d]  256B rows, 16B slots XOR (row&15)
  __shared__ alignas(16) u16 Vs[2][128 * 64];  // [d][kv]  128B rows, 16B slots XOR (row&7)
  __shared__ alignas(16) u16 Ps[8 * 32 * 64];  // per-warp P[q][kv], 16B slots XOR (row&7)
  int id = blockIdx.x;
  int bh = (id & 7) * 4 + ((id >> 3) & 3);     // 4 heads per XCD (K+V^T L2-resident)
  int rest = id >> 5;                          // 0..7
  int pr = rest & 3;                           // q-pair index (256-row q-tiles)
  int par = rest >> 2;                         // K-parity 0/1
  int b = bh >> 4, h = bh & 15;
  int t = threadIdx.x, w = t >> 6, l = t & 63; // w in 0..7
  int l31 = l & 31, hi = l >> 5;
  int l15 = l & 15, lh = l >> 4;               // 16x16 roles (PV)
  size_t base = (size_t)(b * SS) * DD + h * HDD;
  const u16* vtb = VT + (size_t)bh * HDD * SS;
  u16* Ptw = Ps + w * 2048;
  u16* Opar = par ? O1 : O0;
  const float sc2 = 0.12751944557270094f;      // log2(e)/sqrt(128)
  // staging maps: 512 threads cover 1024 16B slots per tile in 2 instrs each
  int ksr[2], kso[2], vsr[2], vso[2];
  #pragma unroll
  for (int i = 0; i < 2; i++) {
    int s = i * 512 + t;
    ksr[i] = s >> 4; kso[i] = ((s & 15) ^ (ksr[i] & 15)) * 8;
    vsr[i] = s >> 3; vso[i] = ((s & 7) ^ (vsr[i] & 7)) * 8;
  }

#define ASTAGE(kb_, bf_) do {                                                           \
    _Pragma("unroll")                                                                   \
    for (int i_ = 0; i_ < 2; i_++)                                                      \
      gl_lds16(K + base + (size_t)((kb_) * 64 + ksr[i_]) * DD + kso[i_],                \
               &Ks[bf_][(i_ * 512 + t) * 8]);                                           \
    _Pragma("unroll")                                                                   \
    for (int i_ = 0; i_ < 2; i_++)                                                      \
      gl_lds16(vtb + (size_t)vsr[i_] * SS + (kb_) * 64 + vso[i_],                       \
               &Vs[bf_][(i_ * 512 + t) * 8]);                                           \
  } while (0)

  for (int half = 0; half < 2; half++) {
    int qt = half ? (7 - pr) : pr;             // 256-row q-tile index
    int qrow = qt * 256 + w * 32 + l31;
    bf16x8 qf[8];
    #pragma unroll
    for (int kt = 0; kt < 8; kt++)
      qf[kt] = *(const bf16x8*)(Q + base + (size_t)qrow * DD + kt * 16 + hi * 8);
    f32x4 cacc[2][8] = {};
    float mrun = -INFINITY, lrun = 0.f;
    int nkb = 4 * qt + 4;                      // K-tiles covering this q-tile
    ASTAGE(par, 0);
    asm volatile("s_waitcnt vmcnt(0)" ::: "memory");
    asm volatile("s_barrier" ::: "memory");
    int it = 0;
    for (int kb = par; kb < nkb; kb += 2, it++) {
      int cur = it & 1;
      if (kb + 2 < nkb) ASTAGE(kb + 2, cur ^ 1);  // in flight during compute(kb)
      const u16* Kc = &Ks[cur][0];
      const u16* Vc = &Vs[cur][0];
      // ---- S^T = K.Q^T : lane owns q-row (col=l31); kv via regs & hi ----
      f32x16 c0 = {}, c1 = {};
      #pragma unroll
      for (int kt = 0; kt < 8; kt++) {
        int sl = (((kt * 2 + hi) ^ (l31 & 15)) * 8);
        bf16x8 kf0 = *(const bf16x8*)(Kc + l31 * 128 + sl);
        bf16x8 kf1 = *(const bf16x8*)(Kc + (32 + l31) * 128 + sl);
        c0 = MFMA32(kf0, qf[kt], c0);
        c1 = MFMA32(kf1, qf[kt], c1);
      }
      if (kb >= 4 * qt) {   // causal mask (diagonal/future tiles only)
        #pragma unroll
        for (int rg = 0; rg < 16; rg++) {
          int kv0 = kb * 64 + (rg & 3) + 8 * (rg >> 2) + 4 * hi;
          if (kv0 > qrow)      c0[rg] = -1e30f;
          if (kv0 + 32 > qrow) c1[rg] = -1e30f;
        }
      }
      // ---- in-register online softmax (exp2-folded) ----
      float ta[16];
      #pragma unroll
      for (int rg = 0; rg < 16; rg++) ta[rg] = fmaxf(c0[rg], c1[rg]);
      #pragma unroll
      for (int off = 8; off > 0; off >>= 1)
        #pragma unroll
        for (int rg = 0; rg < 8; rg++)
          if (rg < off) ta[rg] = fmaxf(ta[rg], ta[rg + off]);
      float pmax = fmaxf(ta[0], __shfl_xor(ta[0], 32));
      if (__any(pmax - mrun > 90.50967f)) {        // defer-max THR=8 (exp units)
        float mnew = fmaxf(mrun, pmax);
        float alpha = __builtin_amdgcn_exp2f((mrun - mnew) * sc2);
        lrun *= alpha;
        #pragma unroll
        for (int m16 = 0; m16 < 2; m16++)
          #pragma unroll
          for (int r = 0; r < 4; r++) {
            float ar = __shfl(alpha, m16 * 16 + lh * 4 + r);
            #pragma unroll
            for (int n2 = 0; n2 < 8; n2++) cacc[m16][n2][r] *= ar;
          }
        mrun = mnew;
      }
      float msc2 = mrun * sc2;
      float ts[16];
      #pragma unroll
      for (int rg = 0; rg < 16; rg++) {
        float p0 = __builtin_amdgcn_exp2f(fmaf(c0[rg], sc2, -msc2)); c0[rg] = p0;
        float p1 = __builtin_amdgcn_exp2f(fmaf(c1[rg], sc2, -msc2)); c1[rg] = p1;
        ts[rg] = p0 + p1;
      }
      #pragma unroll
      for (int off = 8; off > 0; off >>= 1)
        #pragma unroll
        for (int rg = 0; rg < 8; rg++)
          if (rg < off) ts[rg] += ts[rg + off];
      lrun += ts[0] + __shfl_xor(ts[0], 32);
      // ---- P -> per-warp LDS (cvt_pk packing) ----
      #pragma unroll
      for (int q4 = 0; q4 < 4; q4++) {
        uint2 pk0, pk1;
        pk0.x = cvtpk(c0[4 * q4 + 0], c0[4 * q4 + 1]);
        pk0.y = cvtpk(c0[4 * q4 + 2], c0[4 * q4 + 3]);
        pk1.x = cvtpk(c1[4 * q4 + 0], c1[4 * q4 + 1]);
        pk1.y = cvtpk(c1[4 * q4 + 2], c1[4 * q4 + 3]);
        *(uint2*)(Ptw + l31 * 64 + ((q4 ^ (l31 & 7)) * 8 + 4 * hi))       = pk0;
        *(uint2*)(Ptw + l31 * 64 + (((4 + q4) ^ (l31 & 7)) * 8 + 4 * hi)) = pk1;
      }
      // ---- PV (16x16x32): O[q][d] += P.V ----
      #pragma unroll
      for (int ks = 0; ks < 2; ks++) {
        int so = ((ks * 4 + lh) ^ (l15 & 7)) * 8;
        bf16x8 pf0 = *(const bf16x8*)(Ptw + (l15) * 64 + so);
        bf16x8 pf1 = *(const bf16x8*)(Ptw + (16 + l15) * 64 + so);
        #pragma unroll
        for (int n2 = 0; n2 < 8; n2++) {
          bf16x8 vf = *(const bf16x8*)(Vc + (n2 * 16 + l15) * 64 + so);
          cacc[0][n2] = MFMA(pf0, vf, cacc[0][n2]);
          cacc[1][n2] = MFMA(pf1, vf, cacc[1][n2]);
        }
      }
      // ---- post-compute drain: stage(kb+2) landed + all warps done(kb) ----
      asm volatile("s_waitcnt vmcnt(0)" ::: "memory");
      asm volatile("s_barrier" ::: "memory");
    }
    // ---- epilogue: UNNORMALIZED partial O (bf16) + per-row (m,l) ----
    u16* Ob = Opar + (size_t)(bh * 2048 + qt * 256) * 128;
    #pragma unroll
    for (int m16 = 0; m16 < 2; m16++)
      #pragma unroll
      for (int r = 0; r < 4; r++) {
        u16* op = Ob + (size_t)(w * 32 + m16 * 16 + lh * 4 + r) * 128;
        #pragma unroll
        for (int n2 = 0; n2 < 8; n2++)
          op[n2 * 16 + l15] = f2bf(cacc[m16][n2][r]);
      }
    if (l < 32) {
      int uid = bh * 2048 + qt * 256 + w * 32 + l31;
      ml[(size_t)par * 65536 + uid] = make_float2(mrun, lrun);
    }
  }
#undef ASTAGE
}

// ---------------- fused combine + row-quant: parities -> int8 ctx_q ---------
__global__ __launch_bounds__(256) void k_combine_quant(const u16* __restrict__ O0, const u16* __restrict__ O1,
                                                       const float2* __restrict__ ml,
                                                       s8* __restrict__ xq, float* __restrict__ amax) {
  const float sc2 = 0.12751944557270094f;      // log2(e)/sqrt(128)
  int r = blockIdx.x;                          // global token row 0..4095
  int b = r >> 11, qrow = r & 2047;
  int t = threadIdx.x;
  int col = t * 8;
  int h = col >> 7, d0 = col & 127;
  int unit = (b * 16 + h) * 2048 + qrow;
  float2 m0 = ml[unit];
  float2 m1 = ml[65536 + unit];
  float mx = fmaxf(m0.x, m1.x);
  float w0 = __builtin_amdgcn_exp2f((m0.x - mx) * sc2);
  float w1 = __builtin_amdgcn_exp2f((m1.x - mx) * sc2);
  float linv = 1.0f / (w0 * m0.y + w1 * m1.y);
  w0 *= linv; w1 *= linv;
  int4 a  = *(const int4*)(O0 + (size_t)unit * 128 + d0);
  int4 bb = *(const int4*)(O1 + (size_t)unit * 128 + d0);
  const u16* pa = (const u16*)&a;
  const u16* pb = (const u16*)&bb;
  float f[8];
  #pragma unroll
  for (int i = 0; i < 8; i++) f[i] = w0 * bf2f(pa[i]) + w1 * bf2f(pb[i]);
  float m = 0.f;
  #pragma unroll
  for (int i = 0; i < 8; i++) m = fmaxf(m, fabsf(f[i]));
  m = fmaxf(m, __shfl_xor(m, 1));  m = fmaxf(m, __shfl_xor(m, 2));
  m = fmaxf(m, __shfl_xor(m, 4));  m = fmaxf(m, __shfl_xor(m, 8));
  m = fmaxf(m, __shfl_xor(m, 16)); m = fmaxf(m, __shfl_xor(m, 32));
  __shared__ float red[4];
  if ((t & 63) == 0) red[t >> 6] = m;
  __syncthreads();
  m = fmaxf(fmaxf(red[0], red[1]), fmaxf(red[2], red[3]));
  m = fmaxf(m, 1e-8f);                 // clip(amax, 1e-8)
  if (t == 0) amax[r] = m;
  float s = 127.0f / m;                // matches ref: QMAX / a_max
  s8 o[8];
  #pragma unroll
  for (int i = 0; i < 8; i++)
    o[i] = (s8)(int)fminf(127.f, fmaxf(-127.f, rintf(f[i] * s)));
  *(uint2*)(xq + (size_t)r * DD + col) = *(const uint2*)o;
}

// ---------------- launch ----------------------------------------------------
// ws layout (bytes), within the proven 134,348,800 extent:
//   0        scales (4 f32)        256      partials (1024 f64)
//   16384    amax_x                49152    amax_ctx
//   131072   w_q int8 (4 x D*D)  = 16,777,216   (ends 16,908,288)
//   16908288 ml float2 x 2 x 65536 = 1,048,576
//   33685504 x_q int8 (M*D)      =  8,388,608   (region reused as V^T bf16, then ctx_q)
//   50462720 q bf16 | 67239936 k | 84017152 v   (16,777,216 each)
//   84017152 O0 partial bf16 (reuses dead v region after vtrans)
//   117571584 O1 partial bf16    = 16,777,216   (ends 134,348,800)
extern "C" void kernel_launch(void* const* d_in, const int* in_sizes, int n_in,
                              void* d_out, int out_size, void* d_ws, size_t ws_size,
                              hipStream_t stream) {
  const float* x  = (const float*)d_in[0];
  const float* wq = (const float*)d_in[1];
  const float* wk = (const float*)d_in[2];
  const float* wv = (const float*)d_in[3];
  const float* wo = (const float*)d_in[4];
  char* ws = (char*)d_ws;
  float*  scales = (float*)(ws + 0);
  double* part   = (double*)(ws + 256);
  float*  amaxx  = (float*)(ws + 16384);
  float*  amaxc  = (float*)(ws + 49152);
  s8*     wqq    = (s8*)(ws + 131072);
  float2* ml     = (float2*)(ws + 16908288);
  s8*     xq     = (s8*)(ws + 33685504);    // int8 activations; region reused as V^T, ctx_q
  u16*    vt16   = (u16*)(ws + 33685504);
  u16*    qb     = (u16*)(ws + 50462720);
  u16*    kb     = (u16*)(ws + 67239936);
  u16*    vb     = (u16*)(ws + 84017152);
  u16*    O0     = (u16*)(ws + 84017152);   // reuses dead v region
  u16*    O1     = (u16*)(ws + 117571584);
  (void)in_sizes; (void)n_in; (void)out_size; (void)ws_size;

  // fused: rowquant(x) || weight-|.| partial sums  (disjoint buffers)
  k_prep<<<MM + 1024, 256, 0, stream>>>(x, xq, amaxx, wq, wk, wv, wo, part);
  k_wscale_final<<<1, 64, 0, stream>>>(part, scales);
  k_wquant<<<dim3(4096, 4), 256, 0, stream>>>(wq, wk, wv, wo, wqq, scales);
  k_gemm<true, 3, 256><<<768, 512, 0, stream>>>(xq, wqq, amaxx, scales, 0, (void*)qb);
  k_vtrans<<<dim3(32, 2, 32), 256, 0, stream>>>(vb, vt16);
  k_attn<<<256, 512, 0, stream>>>(qb, kb, vt16, O0, O1, ml);
  // fused combine + row-quant straight to int8 (ctx bf16 round-trip removed)
  k_combine_quant<<<MM, 256, 0, stream>>>(O0, O1, ml, xq, amaxc);
  k_gemm<false, 2, 128><<<512, 512, 0, stream>>>(xq, wqq + (size_t)3 * DD * DD, amaxc, scales, 3, d_out);
}